// Round 5
// baseline (85.300 us; speedup 1.0000x reference)
//
#include <hip/hip_runtime.h>
#include <math.h>

#define HIN 32
#define WIN 32
#define NITER 3

// ---------------- input transpose: (n,c,y,x) -> (n,y,x,c) ----------------
__global__ __launch_bounds__(256) void transpose_in(const float* __restrict__ in,
                                                    float* __restrict__ tin) {
    __shared__ float lds[64 * 33];
    const int t = threadIdx.x;
    const int n = blockIdx.x >> 5;
    const int s0 = (blockIdx.x & 31) << 5;  // spatial tile base (y*32+x), 32 wide
    const float* ib = in + n * 65536;
    float* ob = tin + n * 65536;
#pragma unroll
    for (int k = 0; k < 8; ++k) {
        int idx = k * 256 + t;
        int c = idx >> 5, sl = idx & 31;
        lds[c * 33 + sl] = ib[c * 1024 + s0 + sl];  // 128B coalesced runs
    }
    __syncthreads();
#pragma unroll
    for (int k = 0; k < 8; ++k) {
        int idx = k * 256 + t;
        int sl = idx >> 6, c = idx & 63;
        ob[(size_t)(s0 + sl) * 64 + c] = lds[c * 33 + sl];  // 256B coalesced
    }
}

// quad-local sum via DPP (VALU pipe, no LDS): xor1 then xor2 within each quad
template <int CTRL>
__device__ __forceinline__ float qperm_add(float v) {
    int p = __builtin_amdgcn_update_dpp(0, __float_as_int(v), CTRL, 0xF, 0xF, true);
    return v + __int_as_float(p);
}
__device__ __forceinline__ float quad_sum(float v) {
    v = qperm_add<0xB1>(v);  // quad_perm [1,0,3,2] = xor 1
    v = qperm_add<0x4E>(v);  // quad_perm [2,3,0,1] = xor 2
    return v;
}

// ---------------- routing ----------------
// 4 lanes per routing problem (quad-aligned); lane fs owns f-groups
// {2fs, 2fs+1} (input channels fs*16 .. fs*16+15). All reductions are
// quad-local DPP adds. Weight LDS layout XOR-swizzled (bank-conflict-free):
//   (tap,g,m,l) at (tap*8+g)*64 + ((m+g)&7)*8 + l
// TH/TW = valid taps per axis (parity of p/q), T = TH*TW; the other 72-8T
// votes are exactly zero -> contribute Z = 72-8T to the softmax denominator
// (shift-free softmax: logits bounded, no max-subtract needed).
template <int TH, int TW>
__device__ __forceinline__ void route_path(
    const float* __restrict__ tin, const float* __restrict__ wlds,
    float* __restrict__ olds, int n, int p, int q, int g, int fs, int posidx) {
    constexpr int T = TH * TW;
    constexpr float Z = (float)(72 - 8 * T);

    float pri[2][T][8];
#pragma unroll
    for (int i = 0; i < TH; ++i) {
        const int h = (TH == 1) ? 1 : i * 2;
        const int y = (p + h - 1) >> 1;
#pragma unroll
        for (int j = 0; j < TW; ++j) {
            const int w = (TW == 1) ? 1 : j * 2;
            const int x = (q + w - 1) >> 1;
            const int v = i * TW + j;
            const bool valid = (y < HIN) && (x < WIN);
            if (valid) {
                const float4* xp =
                    (const float4*)(tin + (((size_t)n * HIN + y) * WIN + x) * 64 + fs * 16);
                float4 a0 = xp[0], a1 = xp[1], b0 = xp[2], b1 = xp[3];
                const int tap = h * 3 + w;
                const float* wb = wlds + (tap * 8 + g) * 64;
#pragma unroll
                for (int m = 0; m < 8; ++m) {
                    const float4* wp = (const float4*)(wb + ((m + g) & 7) * 8);
                    float4 w0 = wp[0], w1 = wp[1];
                    pri[0][v][m] = a0.x * w0.x + a0.y * w0.y + a0.z * w0.z + a0.w * w0.w +
                                   a1.x * w1.x + a1.y * w1.y + a1.z * w1.z + a1.w * w1.w;
                    pri[1][v][m] = b0.x * w0.x + b0.y * w0.y + b0.z * w0.z + b0.w * w0.w +
                                   b1.x * w1.x + b1.y * w1.y + b1.z * w1.z + b1.w * w1.w;
                }
            } else {
#pragma unroll
                for (int m = 0; m < 8; ++m) { pri[0][v][m] = 0.f; pri[1][v][m] = 0.f; }
            }
        }
    }

    // init: mean over 72 votes (zeros drop out); quad-DPP reduce
    float o[8];
#pragma unroll
    for (int m = 0; m < 8; ++m) {
        float a = 0.f;
#pragma unroll
        for (int v = 0; v < T; ++v) a += pri[0][v][m] + pri[1][v][m];
        o[m] = quad_sum(a) * (1.f / 72.f);
    }

#pragma unroll
    for (int it = 0; it < NITER; ++it) {
        float sn = 0.f;
#pragma unroll
        for (int m = 0; m < 8; ++m) sn += o[m] * o[m];
        const float inv = __builtin_amdgcn_rsqf(fmaxf(sn, 1e-24f));
        float on[8];
#pragma unroll
        for (int m = 0; m < 8; ++m) on[m] = o[m] * inv;

        float r[9];
#pragma unroll
        for (int j = 0; j < 9; ++j) r[j] = 0.f;
#pragma unroll
        for (int f2 = 0; f2 < 2; ++f2)
#pragma unroll
            for (int v = 0; v < T; ++v) {
                float a = 0.f;
#pragma unroll
                for (int m = 0; m < 8; ++m) a += pri[f2][v][m] * on[m];
                const float e = __expf(a);
                r[8] += e;
#pragma unroll
                for (int m = 0; m < 8; ++m) r[m] += e * pri[f2][v][m];
            }
#pragma unroll
        for (int j = 0; j < 9; ++j) r[j] = quad_sum(r[j]);
        const float invs = __builtin_amdgcn_rcpf(r[8] + Z);  // zero votes: exp(0)=1
#pragma unroll
        for (int m = 0; m < 8; ++m) o[m] = r[m] * invs;
    }

    float sn = 0.f;
#pragma unroll
    for (int m = 0; m < 8; ++m) sn += o[m] * o[m];
    const float factor =
        sn * __builtin_amdgcn_rcpf(1.f + sn) * __builtin_amdgcn_rsqf(sn + 1e-12f);

    // lane fs emits m = fs and m = fs+4 (bias applied at store stage)
    float v0 = o[0], v1 = o[4];
#pragma unroll
    for (int m = 1; m < 4; ++m)
        if (fs == m) { v0 = o[m]; v1 = o[m + 4]; }
    olds[(g * 8 + fs) * 9 + posidx] = v0 * factor;
    olds[(g * 8 + fs + 4) * 9 + posidx] = v1 * factor;
}

__global__ __launch_bounds__(256, 4) void caps_routing(
    const float* __restrict__ tin, const float* __restrict__ weight,
    const float* __restrict__ bias, float* __restrict__ out) {
    __shared__ float wlds[4608];  // [tap][g][(m+g)&7][l]
    __shared__ float olds[576];   // [c][posidx], stride 9
    const int t = threadIdx.x;

    // weight staging: shift/mask indexing, taps unrolled (no div/mod)
    {
        const int l = t & 7;
        const int g8 = (t >> 3) & 7;
        const int c = t >> 6;  // m in {2c, 2c+1}
        const float* wsrc = weight + ((l * 8 + g8) * 8 + c * 2) * 9;
        float* wd = wlds + g8 * 64 + l;
#pragma unroll
        for (int mi = 0; mi < 2; ++mi) {
            const int mg = ((c * 2 + mi + g8) & 7) * 8;
#pragma unroll
            for (int kh = 0; kh < 3; ++kh)
#pragma unroll
                for (int kw = 0; kw < 3; ++kw) {
                    const int tap = (2 - kh) * 3 + (2 - kw);
                    wd[tap * 512 + mg] = wsrc[mi * 9 + kh * 3 + kw];
                }
        }
    }
    __syncthreads();

    // lane roles: posidx = wave*2 + half; problem = (posidx, g); lane quad = fs
    const int fs = t & 3;
    const int g = (t >> 2) & 7;
    const int posidx = ((t >> 6) << 1) | ((t >> 5) & 1);  // 0..7

    // block = 8 same-parity positions: b = n*512 + p*8 + j
    const int b = blockIdx.x;
    const int n = b >> 9;
    const int p = (b >> 3) & 63;
    const int j = b & 7;
    const int qpar = j >> 2;
    const int qb = (j & 3) * 16 + qpar;
    const int q = qb + 2 * posidx;

    if (p & 1) {
        if (qpar)
            route_path<2, 2>(tin, wlds, olds, n, p, q, g, fs, posidx);
        else
            route_path<2, 1>(tin, wlds, olds, n, p, q, g, fs, posidx);
    } else {
        if (qpar)
            route_path<1, 2>(tin, wlds, olds, n, p, q, g, fs, posidx);
        else
            route_path<1, 1>(tin, wlds, olds, n, p, q, g, fs, posidx);
    }

    __syncthreads();
    // store: thread t -> channel c = t>>2, pi = t&3; writes q = qb+2*pi, +8
    const int c = t >> 2, pi = t & 3;
    const float bv = bias[c];
    float* obase = out + (((size_t)n * 64 + c) * 64 + p) * 64 + qb;
    obase[2 * pi] = olds[c * 9 + pi] + bv;
    obase[2 * pi + 8] = olds[c * 9 + pi + 4] + bv;
}

extern "C" void kernel_launch(void* const* d_in, const int* in_sizes, int n_in,
                              void* d_out, int out_size, void* d_ws, size_t ws_size,
                              hipStream_t stream) {
    const float* in = (const float*)d_in[0];
    const float* weight = (const float*)d_in[1];
    const float* bias = (const float*)d_in[2];
    float* out = (float*)d_out;
    float* tin = (float*)d_ws;

    transpose_in<<<64, 256, 0, stream>>>(in, tin);
    caps_routing<<<1024, 256, 0, stream>>>(tin, weight, bias, out);
}

// Round 6
// 75.493 us; speedup vs baseline: 1.1299x; 1.1299x over previous
//
#include <hip/hip_runtime.h>
#include <math.h>

#define HIN 32
#define WIN 32
#define NITER 3

// ---------------- input transpose: (n,c,y,x) -> (n,y,x,c) ----------------
__global__ __launch_bounds__(256) void transpose_in(const float* __restrict__ in,
                                                    float* __restrict__ tin) {
    __shared__ float lds[64 * 33];
    const int t = threadIdx.x;
    const int n = blockIdx.x >> 5;
    const int s0 = (blockIdx.x & 31) << 5;  // spatial tile base (y*32+x), 32 wide
    const float* ib = in + n * 65536;
    float* ob = tin + n * 65536;
#pragma unroll
    for (int k = 0; k < 8; ++k) {
        int idx = k * 256 + t;
        int c = idx >> 5, sl = idx & 31;
        lds[c * 33 + sl] = ib[c * 1024 + s0 + sl];  // 128B coalesced runs
    }
    __syncthreads();
#pragma unroll
    for (int k = 0; k < 8; ++k) {
        int idx = k * 256 + t;
        int sl = idx >> 6, c = idx & 63;
        ob[(size_t)(s0 + sl) * 64 + c] = lds[c * 33 + sl];  // 256B coalesced
    }
}

// ---- 8-lane sum entirely on the VALU pipe (DPP), no ds_swizzle ----
// After xor1+xor2 every lane of a quad holds the quad sum; row_half_mirror
// (0x141) swaps the two quads inside each aligned 8-lane group.
template <int CTRL>
__device__ __forceinline__ float dpp_add(float v) {
    int p = __builtin_amdgcn_update_dpp(0, __float_as_int(v), CTRL, 0xF, 0xF, true);
    return v + __int_as_float(p);
}
__device__ __forceinline__ float sum8(float v) {
    v = dpp_add<0xB1>(v);   // quad_perm [1,0,3,2]  = xor 1
    v = dpp_add<0x4E>(v);   // quad_perm [2,3,0,1]  = xor 2
    v = dpp_add<0x141>(v);  // row_half_mirror      = cross-quad in 8-group
    return v;
}

// ---------------- routing ----------------
// Weight LDS layout, XOR-swizzled (bank-conflict-free):
//   (tap,g,m,l) at (tap*8+g)*64 + ((m+g)&7)*8 + l
// TH/TW = valid taps per axis (parity of p/q); T = TH*TW <= 4; the other
// 72-8T votes are exactly zero -> contribute Z = 72-8T to the softmax
// denominator (shift-free softmax: logits bounded, no max-subtract).
// Registers: pri[T][8] <= 32 VGPRs -- stays under the spill cliff (R5 lesson:
// 2 positions/wave spilled at VGPR=64 grant, 21 MB scratch writes).
template <int TH, int TW>
__device__ __forceinline__ void route_path(
    const float* __restrict__ tin, const float* __restrict__ wlds,
    const float* __restrict__ bias, float* __restrict__ olds,
    int n, int p, int q, int g, int s, int lane, int wave) {
    constexpr int T = TH * TW;
    constexpr float Z = (float)(72 - 8 * T);

    float pri[T][8];
#pragma unroll
    for (int i = 0; i < TH; ++i) {
        const int h = (TH == 1) ? 1 : i * 2;
        const int y = (p + h - 1) >> 1;
#pragma unroll
        for (int j = 0; j < TW; ++j) {
            const int w = (TW == 1) ? 1 : j * 2;
            const int x = (q + w - 1) >> 1;
            const int v = i * TW + j;
            const bool valid = (y < HIN) && (x < WIN);
            if (valid) {  // block-uniform path, wave-uniform validity
                float xv[8];
                const float4* xp =
                    (const float4*)(tin + (((size_t)n * HIN + y) * WIN + x) * 64 + s * 8);
                float4 x0 = xp[0], x1 = xp[1];
                xv[0] = x0.x; xv[1] = x0.y; xv[2] = x0.z; xv[3] = x0.w;
                xv[4] = x1.x; xv[5] = x1.y; xv[6] = x1.z; xv[7] = x1.w;
                const int tap = h * 3 + w;
                const float* wb = wlds + (tap * 8 + g) * 64;
#pragma unroll
                for (int m = 0; m < 8; ++m) {
                    const float4* wp = (const float4*)(wb + ((m + g) & 7) * 8);
                    float4 w0 = wp[0], w1 = wp[1];
                    pri[v][m] = xv[0] * w0.x + xv[1] * w0.y + xv[2] * w0.z + xv[3] * w0.w +
                                xv[4] * w1.x + xv[5] * w1.y + xv[6] * w1.z + xv[7] * w1.w;
                }
            } else {
#pragma unroll
                for (int m = 0; m < 8; ++m) pri[v][m] = 0.f;
            }
        }
    }

    // init: mean over 72 votes (zero votes drop out); DPP reduce
    float o[8];
#pragma unroll
    for (int m = 0; m < 8; ++m) {
        float a = 0.f;
#pragma unroll
        for (int v = 0; v < T; ++v) a += pri[v][m];
        o[m] = sum8(a) * (1.f / 72.f);
    }

#pragma unroll
    for (int it = 0; it < NITER; ++it) {
        float sn = 0.f;
#pragma unroll
        for (int m = 0; m < 8; ++m) sn += o[m] * o[m];
        const float inv = __builtin_amdgcn_rsqf(fmaxf(sn, 1e-24f));
        float on[8];
#pragma unroll
        for (int m = 0; m < 8; ++m) on[m] = o[m] * inv;

        float r[9];  // r[0..7] numerators, r[8] = exp-sum
        r[8] = 0.f;
        float e[T];
#pragma unroll
        for (int v = 0; v < T; ++v) {
            float a = 0.f;
#pragma unroll
            for (int m = 0; m < 8; ++m) a += pri[v][m] * on[m];
            e[v] = __expf(a);
            r[8] += e[v];
        }
#pragma unroll
        for (int m = 0; m < 8; ++m) {
            float a = 0.f;
#pragma unroll
            for (int v = 0; v < T; ++v) a += e[v] * pri[v][m];
            r[m] = a;
        }
#pragma unroll
        for (int j = 0; j < 9; ++j) r[j] = sum8(r[j]);
        const float invs = __builtin_amdgcn_rcpf(r[8] + Z);  // zero votes: exp(0)=1
#pragma unroll
        for (int m = 0; m < 8; ++m) o[m] = r[m] * invs;
    }

    float sn = 0.f;
#pragma unroll
    for (int m = 0; m < 8; ++m) sn += o[m] * o[m];
    const float factor =
        sn * __builtin_amdgcn_rcpf(1.f + sn) * __builtin_amdgcn_rsqf(sn + 1e-12f);

    float val = o[0];
#pragma unroll
    for (int m = 1; m < 8; ++m)
        if (s == m) val = o[m];
    val = val * factor + bias[g * 8 + s];

    olds[lane * 5 + wave] = val;
}

__global__ __launch_bounds__(256) void caps_routing(
    const float* __restrict__ tin, const float* __restrict__ weight,
    const float* __restrict__ bias, float* __restrict__ out) {
    __shared__ float wlds[4608];    // [tap][g][(m+g)&7][l]
    __shared__ float olds[64 * 5];  // output staging
    const int t = threadIdx.x;

    // weight staging: shift/mask indexing, taps unrolled (no div/mod)
    {
        const int l = t & 7;
        const int g8 = (t >> 3) & 7;
        const int c = t >> 6;  // m in {2c, 2c+1}
        const float* wsrc = weight + ((l * 8 + g8) * 8 + c * 2) * 9;
        float* wd = wlds + g8 * 64 + l;
#pragma unroll
        for (int mi = 0; mi < 2; ++mi) {
            const int mg = ((c * 2 + mi + g8) & 7) * 8;
#pragma unroll
            for (int kh = 0; kh < 3; ++kh)
#pragma unroll
                for (int kw = 0; kw < 3; ++kw) {
                    const int tap = (2 - kh) * 3 + (2 - kw);
                    wd[tap * 512 + mg] = wsrc[mi * 9 + kh * 3 + kw];
                }
        }
    }
    __syncthreads();

    const int wave = t >> 6;
    const int lane = t & 63;
    const int g = lane >> 3;
    const int s = lane & 7;

    // parity-grouped positions: all 4 waves of a block share (p&1, q&1)
    // b = n*1024 + p*16 + j ; j: qpar = j>>3, qb = (j&7)*8 + qpar
    const int b = blockIdx.x;
    const int n = b >> 10;
    const int p = (b >> 4) & 63;
    const int j = b & 15;
    const int qpar = j >> 3;
    const int qb = (j & 7) * 8 + qpar;
    const int q = qb + 2 * wave;

    if (p & 1) {
        if (qpar)
            route_path<2, 2>(tin, wlds, bias, olds, n, p, q, g, s, lane, wave);
        else
            route_path<2, 1>(tin, wlds, bias, olds, n, p, q, g, s, lane, wave);
    } else {
        if (qpar)
            route_path<1, 2>(tin, wlds, bias, olds, n, p, q, g, s, lane, wave);
        else
            route_path<1, 1>(tin, wlds, bias, olds, n, p, q, g, s, lane, wave);
    }

    __syncthreads();
    // store: c2 = t>>2 (channel), w = t&3 -> q = qb + 2w (stride-2, same parity)
    const int c2 = t >> 2, w = t & 3;
    out[(((size_t)n * 64 + c2) * 64 + p) * 64 + qb + 2 * w] = olds[c2 * 5 + w];
}

extern "C" void kernel_launch(void* const* d_in, const int* in_sizes, int n_in,
                              void* d_out, int out_size, void* d_ws, size_t ws_size,
                              hipStream_t stream) {
    const float* in = (const float*)d_in[0];
    const float* weight = (const float*)d_in[1];
    const float* bias = (const float*)d_in[2];
    float* out = (float*)d_out;
    float* tin = (float*)d_ws;

    transpose_in<<<64, 256, 0, stream>>>(in, tin);
    caps_routing<<<2048, 256, 0, stream>>>(tin, weight, bias, out);
}

// Round 7
// 74.357 us; speedup vs baseline: 1.1472x; 1.0153x over previous
//
#include <hip/hip_runtime.h>
#include <math.h>

#define HIN 32
#define WIN 32
#define NITER 3

// ---------------- input transpose: (n,c,y,x) -> (n,y,x,c) ----------------
__global__ __launch_bounds__(256) void transpose_in(const float* __restrict__ in,
                                                    float* __restrict__ tin) {
    __shared__ float lds[64 * 33];
    const int t = threadIdx.x;
    const int n = blockIdx.x >> 5;
    const int s0 = (blockIdx.x & 31) << 5;  // spatial tile base (y*32+x), 32 wide
    const float* ib = in + n * 65536;
    float* ob = tin + n * 65536;
#pragma unroll
    for (int k = 0; k < 8; ++k) {
        int idx = k * 256 + t;
        int c = idx >> 5, sl = idx & 31;
        lds[c * 33 + sl] = ib[c * 1024 + s0 + sl];  // 128B coalesced runs
    }
    __syncthreads();
#pragma unroll
    for (int k = 0; k < 8; ++k) {
        int idx = k * 256 + t;
        int sl = idx >> 6, c = idx & 63;
        ob[(size_t)(s0 + sl) * 64 + c] = lds[c * 33 + sl];  // 256B coalesced
    }
}

// ---- 8-lane sum entirely on the VALU pipe (DPP), no ds_swizzle ----
template <int CTRL>
__device__ __forceinline__ float dpp_add(float v) {
    int p = __builtin_amdgcn_update_dpp(0, __float_as_int(v), CTRL, 0xF, 0xF, true);
    return v + __int_as_float(p);
}
__device__ __forceinline__ float sum8(float v) {
    v = dpp_add<0xB1>(v);   // quad_perm [1,0,3,2]  = xor 1
    v = dpp_add<0x4E>(v);   // quad_perm [2,3,0,1]  = xor 2
    v = dpp_add<0x141>(v);  // row_half_mirror      = cross-quad in 8-group
    return v;
}

// ---------------- routing (staging + compute, per parity path) ----------------
// Parity-grouped blocks use only T = TH*TW taps, so stage ONLY those: T*512
// weight elements. Thread mapping e = k*256 + t gives pure bit-field decode
// (vtap = k/2 compile-time, l = (k&1)*4 + t>>6, g = (t>>3)&7, m = t&7).
// wlds row stride 68 floats: staging writes land 2-way banked (free), routing
// float4 reads tile all 32 banks (conflict-free), rows stay 16B-aligned.
// The other 72-8T votes are exactly zero -> contribute Z = 72-8T to the
// softmax denominator (shift-free softmax: bounded logits, no max-subtract).
// R5 lesson: keep pri <= 32 VGPRs (1 position/wave) -- spill cliff at 2 pos.
template <int TH, int TW>
__device__ __forceinline__ void run_path(
    const float* __restrict__ tin, const float* __restrict__ weight,
    const float* __restrict__ bias, float* __restrict__ out,
    float* __restrict__ wlds, float* __restrict__ olds,
    int t, int n, int p, int qb) {
    constexpr int T = TH * TW;
    constexpr float Z = (float)(72 - 8 * T);

    // ---- stage T taps of flipped weight ----
    {
        const int g = (t >> 3) & 7;
        const int m = t & 7;
        const int mg = ((m + g) & 7) * 8;
        const int l0 = t >> 6;
#pragma unroll
        for (int k = 0; k < 2 * T; ++k) {
            const int vtap = k >> 1;
            const int chunk = k & 1;
            const int hh = (TH == 1) ? 1 : ((vtap / TW) * 2);
            const int ww = (TW == 1) ? 1 : ((vtap % TW) * 2);
            const int jflip = (2 - hh) * 3 + (2 - ww);  // compile-time
            const int l = chunk * 4 + l0;
            wlds[(vtap * 8 + g) * 68 + mg + l] =
                weight[(chunk * 256 + t) * 9 + jflip];
        }
    }
    __syncthreads();

    const int wave = t >> 6;
    const int lane = t & 63;
    const int g = lane >> 3;
    const int s = lane & 7;
    const int q = qb + 2 * wave;

    // ---- priors ----
    float pri[T][8];
#pragma unroll
    for (int i = 0; i < TH; ++i) {
        const int h = (TH == 1) ? 1 : i * 2;
        const int y = (p + h - 1) >> 1;
#pragma unroll
        for (int j = 0; j < TW; ++j) {
            const int v = i * TW + j;
            const int w = (TW == 1) ? 1 : j * 2;
            const int x = (q + w - 1) >> 1;
            const bool valid = (y < HIN) && (x < WIN);
            if (valid) {  // block-uniform path, wave-uniform validity
                float xv[8];
                const float4* xp =
                    (const float4*)(tin + (((size_t)n * HIN + y) * WIN + x) * 64 + s * 8);
                float4 x0 = xp[0], x1 = xp[1];
                xv[0] = x0.x; xv[1] = x0.y; xv[2] = x0.z; xv[3] = x0.w;
                xv[4] = x1.x; xv[5] = x1.y; xv[6] = x1.z; xv[7] = x1.w;
                const float* wb = wlds + (v * 8 + g) * 68;
#pragma unroll
                for (int m = 0; m < 8; ++m) {
                    const float4* wp = (const float4*)(wb + ((m + g) & 7) * 8);
                    float4 w0 = wp[0], w1 = wp[1];
                    pri[v][m] = xv[0] * w0.x + xv[1] * w0.y + xv[2] * w0.z + xv[3] * w0.w +
                                xv[4] * w1.x + xv[5] * w1.y + xv[6] * w1.z + xv[7] * w1.w;
                }
            } else {
#pragma unroll
                for (int m = 0; m < 8; ++m) pri[v][m] = 0.f;
            }
        }
    }

    // ---- init: mean over 72 votes (zero votes drop out) ----
    float o[8];
#pragma unroll
    for (int m = 0; m < 8; ++m) {
        float a = 0.f;
#pragma unroll
        for (int v = 0; v < T; ++v) a += pri[v][m];
        o[m] = sum8(a) * (1.f / 72.f);
    }

    // ---- 3 routing iterations ----
#pragma unroll
    for (int it = 0; it < NITER; ++it) {
        float sn = 0.f;
#pragma unroll
        for (int m = 0; m < 8; ++m) sn += o[m] * o[m];
        const float inv = __builtin_amdgcn_rsqf(fmaxf(sn, 1e-24f));
        float on[8];
#pragma unroll
        for (int m = 0; m < 8; ++m) on[m] = o[m] * inv;

        float r[9];  // r[0..7] numerators, r[8] = exp-sum
        r[8] = 0.f;
        float e[T];
#pragma unroll
        for (int v = 0; v < T; ++v) {
            float a = 0.f;
#pragma unroll
            for (int m = 0; m < 8; ++m) a += pri[v][m] * on[m];
            e[v] = __expf(a);
            r[8] += e[v];
        }
#pragma unroll
        for (int m = 0; m < 8; ++m) {
            float a = 0.f;
#pragma unroll
            for (int v = 0; v < T; ++v) a += e[v] * pri[v][m];
            r[m] = a;
        }
#pragma unroll
        for (int j = 0; j < 9; ++j) r[j] = sum8(r[j]);
        const float invs = __builtin_amdgcn_rcpf(r[8] + Z);  // zero votes: exp(0)=1
#pragma unroll
        for (int m = 0; m < 8; ++m) o[m] = r[m] * invs;
    }

    // ---- squash + emit ----
    float sn = 0.f;
#pragma unroll
    for (int m = 0; m < 8; ++m) sn += o[m] * o[m];
    const float factor =
        sn * __builtin_amdgcn_rcpf(1.f + sn) * __builtin_amdgcn_rsqf(sn + 1e-12f);

    float val = o[0];
#pragma unroll
    for (int m = 1; m < 8; ++m)
        if (s == m) val = o[m];
    val = val * factor + bias[g * 8 + s];

    olds[lane * 5 + wave] = val;

    __syncthreads();
    // store: c2 = t>>2 (channel), w = t&3 -> q = qb + 2w (stride-2, same parity)
    const int c2 = t >> 2, w = t & 3;
    out[(((size_t)n * 64 + c2) * 64 + p) * 64 + qb + 2 * w] = olds[c2 * 5 + w];
}

__global__ __launch_bounds__(256) void caps_routing(
    const float* __restrict__ tin, const float* __restrict__ weight,
    const float* __restrict__ bias, float* __restrict__ out) {
    __shared__ float wlds[4 * 8 * 68];  // [vtap][g][(m+g)&7][l], stride-68 rows
    __shared__ float olds[64 * 5];      // output staging
    const int t = threadIdx.x;

    // parity-grouped positions: all 4 waves of a block share (p&1, q&1)
    // b = n*1024 + p*16 + j ; j: qpar = j>>3, qb = (j&7)*8 + qpar
    const int b = blockIdx.x;
    const int n = b >> 10;
    const int p = (b >> 4) & 63;
    const int j = b & 15;
    const int qpar = j >> 3;
    const int qb = (j & 7) * 8 + qpar;

    if (p & 1) {
        if (qpar)
            run_path<2, 2>(tin, weight, bias, out, wlds, olds, t, n, p, qb);
        else
            run_path<2, 1>(tin, weight, bias, out, wlds, olds, t, n, p, qb);
    } else {
        if (qpar)
            run_path<1, 2>(tin, weight, bias, out, wlds, olds, t, n, p, qb);
        else
            run_path<1, 1>(tin, weight, bias, out, wlds, olds, t, n, p, qb);
    }
}

extern "C" void kernel_launch(void* const* d_in, const int* in_sizes, int n_in,
                              void* d_out, int out_size, void* d_ws, size_t ws_size,
                              hipStream_t stream) {
    const float* in = (const float*)d_in[0];
    const float* weight = (const float*)d_in[1];
    const float* bias = (const float*)d_in[2];
    float* out = (float*)d_out;
    float* tin = (float*)d_ws;

    transpose_in<<<64, 256, 0, stream>>>(in, tin);
    caps_routing<<<2048, 256, 0, stream>>>(tin, weight, bias, out);
}